// Round 13
// baseline (69.015 us; speedup 1.0000x reference)
//
#include <hip/hip_runtime.h>

// PolarConv v12 == v11 (rank-collapse: G_q[h,i] = sum_e h2*f, then one W3
// contraction per 8 queries) with the latency fix: v11's per-pair
// sched_barrier(0) serialized the 4 INDEPENDENT pair-chains back-to-back
// (VALU 35%, MFMA 5.6%, all pipes idle; VGPR 68 = over-constrained).
//  1. No per-pp barriers; neighbor-xyz for all 4 pairs loaded upfront ->
//     compiler overlaps the 4 chains (each ~300cy of serial latency).
//  2. Contraction ds-read hoist capped at 8 chunks instead of 4.
// Math identical to v11 (absmax must remain 6.0). Spill tripwire: WRITE_SIZE.

constexpr int THREADS = 256;
constexpr int NBLOCKS = 1568;

typedef __attribute__((ext_vector_type(8)))  short short8;    // 8 bf16
typedef __attribute__((ext_vector_type(16))) float floatx16;
typedef __attribute__((ext_vector_type(4)))  float floatx4;

#define MFMA32(a, b, c) __builtin_amdgcn_mfma_f32_32x32x16_bf16((a), (b), (c), 0, 0, 0)
#define MFMA16(a, b, c) __builtin_amdgcn_mfma_f32_16x16x32_bf16((a), (b), (c), 0, 0, 0)

static __device__ inline short f2bf(float x) {
  __bf16 b = (__bf16)x;
  return __builtin_bit_cast(short, b);
}
static __device__ inline unsigned pk2(float lo, float hi) {
  unsigned l = (unsigned short)__builtin_bit_cast(unsigned short, f2bf(lo));
  unsigned h = (unsigned short)__builtin_bit_cast(unsigned short, f2bf(hi));
  return (h << 16) | l;
}
// v_permlane32_swap: a' = {a.lo, b.lo}, b' = {a.hi, b.hi} (half exchange)
static __device__ inline void pl32swap(float& a, float& b) {
  asm volatile("v_permlane32_swap_b32 %0, %1" : "+v"(a), "+v"(b));
}
static __device__ inline short8 pack8(const float* v) {
  union { unsigned u[4]; short8 s; } r;
  r.u[0] = pk2(v[0], v[1]); r.u[1] = pk2(v[2], v[3]);
  r.u[2] = pk2(v[4], v[5]); r.u[3] = pk2(v[6], v[7]);
  return r.s;
}

__global__ __launch_bounds__(THREADS, 3) void polarconv_v12(
    const float* __restrict__ feats,   // [N,16]
    const float* __restrict__ xyz,     // [N,3]
    const int*   __restrict__ nbr,     // [E]
    const float* __restrict__ dist,    // [E]
    const float* __restrict__ W1,      // [4,32]
    const float* __restrict__ b1,      // [32]
    const float* __restrict__ W2,      // [32,32]
    const float* __restrict__ b2,      // [32]
    const float* __restrict__ W3,      // [32,256]
    const float* __restrict__ b3,      // [256]
    float* __restrict__ out,           // [Nq,16]
    int Nq)
{
  const int tid  = threadIdx.x;
  const int lane = tid & 63;
  const int wv   = tid >> 6;
  const int col  = lane & 31;
  const int g2   = lane >> 5;
  const int i16  = col & 15;

  // W3f A-table: chunk c, lane ln(o=ln&15, kg=ln>>4), slot j:
  //   c<16: W3[(8kg+j), c*16+o]; c==16 (F): kg<2 ? b3[(8kg+j)*16+o] : 0
  __shared__ alignas(16) short8 sW3[17 * 64];          // 17408 B
  __shared__ alignas(16) char   sGb[4][8704];          // per-wave G buffer

  for (int s = tid; s < 17 * 64; s += THREADS) {
    const int c = s >> 6, ln = s & 63;
    const int o = ln & 15, kg = ln >> 4;
    short8 v;
#pragma unroll
    for (int j = 0; j < 8; ++j) {
      short x = 0;
      if (c < 16)      x = f2bf(W3[(8 * kg + j) * 256 + c * 16 + o]);
      else if (kg < 2) x = f2bf(b3[(8 * kg + j) * 16 + o]);
      v[j] = x;
    }
    sW3[s] = v;
  }
  char* gbase = sGb[wv];
  if (lane < 16) {   // zero F-chunk kg=2,3 (A zeros * LDS NaN-garbage hazard)
    short8 z;
#pragma unroll
    for (int j = 0; j < 8; ++j) z[j] = 0;
    const int q = lane >> 1, kg = 2 + (lane & 1);
    *reinterpret_cast<short8*>(gbase + ((128 + q) * 4 + kg) * 16) = z;
  }
  __syncthreads();

  // ---- static per-lane fragments ----
  short8 a1;   // L1 A (swapped): A[m=h1dim=col, k=8g2+j] = W1[j,col] / b1 row
#pragma unroll
  for (int j = 0; j < 8; ++j) {
    short v = 0;
    if (g2 == 0) {
      if (j < 4)       v = f2bf(W1[j * 32 + col]);
      else if (j == 4) v = f2bf(b1[col]);
    }
    a1[j] = v;
  }
  short8 w2b0, w2b1;   // L2 B: B[k1, n=h=col] = W2[k1*32+col], k1 split 0-15/16-31
#pragma unroll
  for (int j = 0; j < 8; ++j) {
    w2b0[j] = f2bf(W2[(8 * g2 + j) * 32 + col]);
    w2b1[j] = f2bf(W2[(16 + 8 * g2 + j) * 32 + col]);
  }
  const float    b2v = b2[col];
  const unsigned mlo = (col < 16) ? 0xFFFFFFFFu : 0u;
  const unsigned mhi = ~mlo;

  floatx16 z16;
#pragma unroll
  for (int m = 0; m < 16; ++m) z16[m] = 0.f;

  const int E    = Nq * 16;
  const int nss  = (Nq + 7) >> 3;
  const int wid  = blockIdx.x * 4 + wv;
  const int nw   = NBLOCKS * 4;
  const int tb   = ((col & 16) + 8 * g2) * 4;   // bpermute source-lane byte base

  for (int s = wid; s < nss; s += nw) {
    const int ebase = s * 128;
    int nbv[4]; float dv[4], cxv[4], cyv[4], czv[4];
#pragma unroll
    for (int pp = 0; pp < 4; ++pp) {
      const int e = min(ebase + pp * 32 + col, E - 1);
      nbv[pp] = nbr[e];
      dv[pp]  = dist[e];
      const int qc = min(s * 8 + pp * 2 + (col >> 4), Nq - 1);
      cxv[pp] = xyz[3 * qc]; cyv[pp] = xyz[3 * qc + 1]; czv[pp] = xyz[3 * qc + 2];
    }
    // all 4 pairs' neighbor xyz upfront (no cross-pp serial rotation)
    float nxv[4], nyv[4], nzv[4];
#pragma unroll
    for (int pp = 0; pp < 4; ++pp) {
      nxv[pp] = xyz[3 * nbv[pp]];
      nyv[pp] = xyz[3 * nbv[pp] + 1];
      nzv[pp] = xyz[3 * nbv[pp] + 2];
    }

#pragma unroll
    for (int pp = 0; pp < 4; ++pp) {
      // transposed f gathers: lane(col,g2) reads f[e=16ch+8g2+j, i16] via
      // nbr broadcast from edge-lane (ds_bpermute) -> 4x64B coalesced rows
      float fj[8];
#pragma unroll
      for (int j = 0; j < 8; ++j) {
        const int row = __builtin_amdgcn_ds_bpermute(tb + 4 * j, nbv[pp]);
        fj[j] = feats[(size_t)row * 16 + i16];
      }

      // polar (per edge-lane, dup across g2)
      const float rr  = sqrtf(dv[pp] + 1e-7f);
      const float inv = 1.0f / rr;
      const float p0 = rr;
      const float p1 = (nxv[pp] - cxv[pp]) * inv;
      const float p2 = (nzv[pp] - czv[pp]) * inv;
      const float p3 = (nyv[pp] - cyv[pp]) * inv;

      short8 bp;   // L1 B: B[k=d, n=e=col]: polar + bias-row 1.0 (g2==0 only)
      bp[0] = (g2 == 0) ? f2bf(p0) : (short)0;
      bp[1] = (g2 == 0) ? f2bf(p1) : (short)0;
      bp[2] = (g2 == 0) ? f2bf(p2) : (short)0;
      bp[3] = (g2 == 0) ? f2bf(p3) : (short)0;
      bp[4] = (g2 == 0) ? (short)0x3F80 : (short)0;
      bp[5] = 0; bp[6] = 0; bp[7] = 0;

      // L1 (swapped): D1[m=h1dim rows, n=e lanes]
      floatx16 d1 = MFMA32(a1, bp, z16);
      float r1[16];
#pragma unroll
      for (int m = 0; m < 16; ++m) r1[m] = fmaxf(d1[m], 0.0f);

      // repack rows->slots: L2 A[m=e=col, k=k1]: swaps (r_i, r_{4+i})
      float q0j[8], q1j[8];
#pragma unroll
      for (int i = 0; i < 4; ++i) {
        float x = r1[i], y = r1[4 + i];
        pl32swap(x, y);
        q0j[i] = x; q0j[4 + i] = y;          // k1 = 8g2 + j
        x = r1[8 + i]; y = r1[12 + i];
        pl32swap(x, y);
        q1j[i] = x; q1j[4 + i] = y;          // k1 = 16 + 8g2 + j
      }
      const short8 A2a = pack8(q0j), A2b = pack8(q1j);

      // L2 (unswapped): D2[m=e rows, n=h lanes]
      floatx16 t2 = MFMA32(A2a, w2b0, z16);
      floatx16 d2 = MFMA32(A2b, w2b1, t2);
      float h2[16];
#pragma unroll
      for (int m = 0; m < 16; ++m) h2[m] = fmaxf(d2[m] + b2v, 0.0f);

      // repack: G A[m=h=col, k=e_local]: same swap pattern
      float a0j[8], a1j[8];
#pragma unroll
      for (int i = 0; i < 4; ++i) {
        float x = h2[i], y = h2[4 + i];
        pl32swap(x, y);
        a0j[i] = x; a0j[4 + i] = y;          // q0 edges e = 8g2+j
        x = h2[8 + i]; y = h2[12 + i];
        pl32swap(x, y);
        a1j[i] = x; a1j[4 + i] = y;          // q1 edges
      }
      const short8 GA0 = pack8(a0j), GA1 = pack8(a1j);

      // G B-frags: masked halves (cols<16 = q0 data, cols>=16 = q1 data)
      union { unsigned u[4]; short8 s; } gb0, gb1;
      const unsigned pf0 = pk2(fj[0], fj[1]), pf1 = pk2(fj[2], fj[3]);
      const unsigned pf2 = pk2(fj[4], fj[5]), pf3 = pk2(fj[6], fj[7]);
      gb0.u[0] = pf0 & mlo; gb0.u[1] = pf1 & mlo; gb0.u[2] = pf2 & mlo; gb0.u[3] = pf3 & mlo;
      gb1.u[0] = pf0 & mhi; gb1.u[1] = pf1 & mhi; gb1.u[2] = pf2 & mhi; gb1.u[3] = pf3 & mhi;

      // G: chained, cols<16 = G_q0, cols>=16 = G_q1
      floatx16 g = MFMA32(GA1, gb1.s, z16);
      g = MFMA32(GA0, gb0.s, g);

      // F[q,i] = sum_e f[e,i]: own 8 + other g2-half
      float sF = fj[0] + fj[1] + fj[2] + fj[3] + fj[4] + fj[5] + fj[6] + fj[7];
      sF += __shfl_xor(sF, 32, 64);

      // write G (k-order i*32+h): slot=((i*8+q)*4+kg)*16 + g2*8, XOR swz(i)
      const int q    = 2 * pp + (col >> 4);
      const int swz  = (i16 & 7) << 4;
      const int sb   = (i16 * 8 + q) * 64 + g2 * 8;
#pragma unroll
      for (int kg = 0; kg < 4; ++kg) {
        uint2 w;
        w.x = pk2(g[4 * kg + 0], g[4 * kg + 1]);
        w.y = pk2(g[4 * kg + 2], g[4 * kg + 3]);
        *reinterpret_cast<uint2*>(gbase + ((sb + kg * 16) ^ swz)) = w;
      }
      if (g2 == 0)
        *reinterpret_cast<short*>(gbase + ((128 + q) * 4 + (i16 >> 3)) * 16 +
                                  (i16 & 7) * 2) = f2bf(sF);
    }

    // contraction: D[o, q] = sum_{17 chunks} W3f_c x G_c  (2 acc chains)
    floatx4 acc0 = {0.f, 0.f, 0.f, 0.f}, acc1 = {0.f, 0.f, 0.f, 0.f};
    const int qr = lane & 7, kgr = lane >> 4;
#pragma unroll
    for (int c = 0; c < 17; ++c) {
      const short8 af = sW3[c * 64 + lane];
      const short8 bf = *reinterpret_cast<const short8*>(
          gbase + (((c * 8 + qr) * 4 + kgr) * 16 ^ ((c & 7) << 4)));
      if (c & 1) acc1 = MFMA16(af, bf, acc1);
      else       acc0 = MFMA16(af, bf, acc0);
      if ((c & 7) == 7) __builtin_amdgcn_sched_barrier(0);
    }
    const int qg = s * 8 + (lane & 15);
    if ((lane & 15) < 8 && qg < Nq) {
      float4 v = {acc0[0] + acc1[0], acc0[1] + acc1[1],
                  acc0[2] + acc1[2], acc0[3] + acc1[3]};
      *reinterpret_cast<float4*>(out + (size_t)qg * 16 + (lane >> 4) * 4) = v;
    }
  }
}

extern "C" void kernel_launch(void* const* d_in, const int* in_sizes, int n_in,
                              void* d_out, int out_size, void* d_ws, size_t ws_size,
                              hipStream_t stream) {
  const float* feats = (const float*)d_in[0];
  const float* xyz   = (const float*)d_in[1];
  const int*   nbr   = (const int*)d_in[2];
  // d_in[3] = neighbors_row_splits: uniform arange*16 for this problem
  const float* dist  = (const float*)d_in[4];
  const float* W1 = (const float*)d_in[5];
  const float* b1 = (const float*)d_in[6];
  const float* W2 = (const float*)d_in[7];
  const float* b2 = (const float*)d_in[8];
  const float* W3 = (const float*)d_in[9];
  const float* b3 = (const float*)d_in[10];
  float* out = (float*)d_out;

  const int Nq = in_sizes[3] - 1;

  polarconv_v12<<<NBLOCKS, THREADS, 0, stream>>>(
      feats, xyz, nbr, dist, W1, b1, W2, b2, W3, b3, out, Nq);
}

// Round 15
// 56.986 us; speedup vs baseline: 1.2111x; 1.2111x over previous
//
#include <hip/hip_runtime.h>

// PolarConv v14 == exact revert to v10 (round-10 passer: 57.03us, absmax 4.5,
// clean post-timing validation). v13's f-prefetch across the loop backedge was
// perf-neutral (57.98us) but caused post-timing divergence across graph
// replays -> reverted wholesale. Structure: 2 queries (32 edges) per wave
// iteration, 32x32x16 MFMAs; W3 table in shared LDS (conflict-free identity
// lane layout); f as packed bf16 dwords; b2 bias via SGPR+cndmask at bh2
// build; b3 via one MFMA; DPP-butterfly segment sum; no atomics, no spill.

constexpr int THREADS = 256;
constexpr int NBLOCKS = 1024;

typedef __attribute__((ext_vector_type(8)))  short short8;    // 8 bf16
typedef __attribute__((ext_vector_type(4)))  int   intx4;
typedef __attribute__((ext_vector_type(16))) float floatx16;
typedef __attribute__((ext_vector_type(2)))  float floatx2;

static __device__ inline short f2bf(float x) {
  __bf16 b = (__bf16)x;
  return __builtin_bit_cast(short, b);
}
static __device__ inline unsigned pk2(float lo, float hi) {
  unsigned l = (unsigned short)__builtin_bit_cast(unsigned short, f2bf(lo));
  unsigned h = (unsigned short)__builtin_bit_cast(unsigned short, f2bf(hi));
  return (h << 16) | l;
}

// x += dpp_shuffled(x); CTRL: 0xB1 xor1, 0x4E xor2, 0x124 ror4, 0x128 ror8
template <int CTRL>
static __device__ inline float dpp_add(float x) {
  int y = __builtin_amdgcn_update_dpp(0, __builtin_bit_cast(int, x),
                                      CTRL, 0xF, 0xF, true);
  return x + __builtin_bit_cast(float, y);
}

__global__ __launch_bounds__(THREADS, 2) void polarconv_v14(
    const float* __restrict__ feats,   // [N,16]
    const float* __restrict__ xyz,     // [N,3]
    const int*   __restrict__ nbr,     // [E]
    const float* __restrict__ dist,    // [E]
    const float* __restrict__ W1,      // [4,32]
    const float* __restrict__ b1,      // [32]
    const float* __restrict__ W2,      // [32,32]
    const float* __restrict__ b2,      // [32]
    const float* __restrict__ W3,      // [32,256]
    const float* __restrict__ b3,      // [256]
    float* __restrict__ out,           // [Nq,16]
    int Nq)
{
  const int tid  = threadIdx.x;
  const int lane = tid & 63;
  const int col  = lane & 31;   // edge slot within pair-tile; also A-operand row
  const int g2   = lane >> 5;   // k-group / o-half
  const int qh   = col >> 4;    // which query of the pair
  const int c16  = col & 15;
  const int E    = Nq * 16;

  // ---- shared W3 table: slot s = (t2*2+h)*64 + lane, 16B frag per slot ----
  __shared__ alignas(16) short sBU[1024 * 8];   // 16 KB
  short8* sBU8 = reinterpret_cast<short8*>(sBU);
  for (int s = tid; s < 1024; s += THREADS) {
    const int t2h = s >> 6, ln = s & 63;
    const int t2 = t2h >> 1, h = t2h & 1;
    const int cc = ln & 31, gg = ln >> 5;
    short8 v;
#pragma unroll
    for (int j = 0; j < 8; ++j)
      v[j] = f2bf(W3[(16 * h + (j & 3) + 8 * (j >> 2) + 4 * gg) * 256 + t2 * 32 + cc]);
    sBU8[s] = v;
  }
  __syncthreads();
  const short8* buP = sBU8 + lane;   // identity lane->slot base

  // sigma(h,j) = 16h + (j&3) + 8*(j>>2) + 4*g2  (== C/D row layout)
  // ---------------- small per-lane fragments (stay in VGPRs) ----------------
  short8 a1;                    // L1 A: A[row=col, k=8g2+j]
#pragma unroll
  for (int j = 0; j < 8; ++j) {
    short v = 0;
    if (g2 == 0) {
      if (j < 4)       v = f2bf(W1[j * 32 + col]);
      else if (j == 4) v = f2bf(b1[col]);
    }
    a1[j] = v;
  }
  short8 a2k[2];                // L2 A: W2[sigma(h,j)*32 + row]
#pragma unroll
  for (int h = 0; h < 2; ++h)
#pragma unroll
    for (int j = 0; j < 8; ++j)
      a2k[h][j] = f2bf(W2[(16 * h + (j & 3) + 8 * (j >> 2) + 4 * g2) * 32 + col]);
  short8 ab3;                   // b3 A: A[row<16, k=8g2+j] = b3[k*16+row]
#pragma unroll
  for (int j = 0; j < 8; ++j)
    ab3[j] = (col < 16) ? f2bf(b3[(8 * g2 + j) * 16 + col]) : (short)0;

  floatx16 z16;
#pragma unroll
  for (int m = 0; m < 16; ++m) z16[m] = 0.0f;

  const int wid   = blockIdx.x * (THREADS / 64) + (tid >> 6);
  const int STR   = NBLOCKS * (THREADS / 64);
  const int pairs = (Nq + 1) >> 1;
  int p = wid;
  if (p >= pairs) return;

  // ---------------- prefetch state for iteration p ----------------
  int   nbN;
  float dN, cxN, cyN, czN, nxN, nyN, nzN;
  {
    const int e = min(p * 32 + col, E - 1);
    nbN = nbr[e];
    dN  = dist[e];
    const int qc = min(2 * p + qh, Nq - 1);
    cxN = xyz[3 * qc]; cyN = xyz[3 * qc + 1]; czN = xyz[3 * qc + 2];
    nxN = xyz[3 * nbN]; nyN = xyz[3 * nbN + 1]; nzN = xyz[3 * nbN + 2];
  }

  for (; p < pairs; p += STR) {
    const int   nbA = nbN;
    const float dA = dN, cx = cxN, cy = cyN, cz = czN;
    const float nx = nxN, ny = nyN, nz = nzN;

    // current feats gather (consumed after the L1/L2 chain -> latency hidden)
    const float4* fp = reinterpret_cast<const float4*>(feats + (size_t)nbA * 16);
    float4 v0 = fp[0], v1 = fp[1], v2 = fp[2], v3 = fp[3];

    // prefetch next pair's {nbr, dist, centers}
    const int pc = min(p + STR, pairs - 1);
    {
      const int e2 = min(pc * 32 + col, E - 1);
      nbN = nbr[e2];
      dN  = dist[e2];
      const int qc2 = min(2 * pc + qh, Nq - 1);
      cxN = xyz[3 * qc2]; cyN = xyz[3 * qc2 + 1]; czN = xyz[3 * qc2 + 2];
    }

    // ---- polar (f32) ----
    const float rr  = sqrtf(dA + 1e-7f);
    const float inv = 1.0f / rr;
    const float q0 = rr;
    const float q1 = (nx - cx) * inv;
    const float q2 = (nz - cz) * inv;
    const float q3 = (ny - cy) * inv;

    // L1 B-frag: B[k=8g2+j, col] = polar'[k] (k<4 polar, k==4 -> 1.0 bias row)
    short8 bp;
    bp[0] = (g2 == 0) ? f2bf(q0) : (short)0;
    bp[1] = (g2 == 0) ? f2bf(q1) : (short)0;
    bp[2] = (g2 == 0) ? f2bf(q2) : (short)0;
    bp[3] = (g2 == 0) ? f2bf(q3) : (short)0;
    bp[4] = (g2 == 0) ? (short)0x3F80 : (short)0;   // bf16(1.0)
    bp[5] = 0; bp[6] = 0; bp[7] = 0;

    // ---- L1: one 32x32x16 MFMA -> all 32 h1-dims ----
    floatx16 d1 = __builtin_amdgcn_mfma_f32_32x32x16_bf16(a1, bp, z16, 0, 0, 0);
    short8 bh1k0, bh1k1;
#pragma unroll
    for (int j = 0; j < 8; ++j) {
      bh1k0[j] = f2bf(fmaxf(d1[j], 0.0f));        // h1[sigma(0,j)]
      bh1k1[j] = f2bf(fmaxf(d1[8 + j], 0.0f));    // h1[sigma(1,j)]
    }

    // ---- L2: 2 chained MFMAs, zero C; bias b2 applied below via SGPR+cnd ----
    floatx16 t0 = __builtin_amdgcn_mfma_f32_32x32x16_bf16(a2k[0], bh1k0, z16, 0, 0, 0);
    floatx16 d2 = __builtin_amdgcn_mfma_f32_32x32x16_bf16(a2k[1], bh1k1, t0, 0, 0, 0);
    short8 bh2k0, bh2k1;
#pragma unroll
    for (int j = 0; j < 8; ++j) {
      const int c0 = (j & 3) + 8 * (j >> 2);      // sigma with g2=0
      const float bl0 = g2 ? b2[c0 + 4]      : b2[c0];        // SGPR pair + cndmask
      const float bl1 = g2 ? b2[16 + c0 + 4] : b2[16 + c0];
      bh2k0[j] = f2bf(fmaxf(d2[j]     + bl0, 0.0f));
      bh2k1[j] = f2bf(fmaxf(d2[8 + j] + bl1, 0.0f));
    }

    // issue next pair's dependent xyz[nb] gather (nbN arrived by now)
    nxN = xyz[3 * nbN]; nyN = xyz[3 * nbN + 1]; nzN = xyz[3 * nbN + 2];

    // ---- neighbor features: pack to 8 bf16x2 dwords (releases v0..v3) ----
    unsigned fpk0 = pk2(v0.x, v0.y), fpk1 = pk2(v0.z, v0.w);
    unsigned fpk2 = pk2(v1.x, v1.y), fpk3 = pk2(v1.z, v1.w);
    unsigned fpk4 = pk2(v2.x, v2.y), fpk5 = pk2(v2.z, v2.w);
    unsigned fpk6 = pk2(v3.x, v3.y), fpk7 = pk2(v3.z, v3.w);

    // ---- b3 term: B[k=8g2+j, col] = f[col, k] -> dwords fpk[4g2 + 0..3] ----
    intx4 bsel;
    bsel[0] = (int)(g2 ? fpk4 : fpk0);
    bsel[1] = (int)(g2 ? fpk5 : fpk1);
    bsel[2] = (int)(g2 ? fpk6 : fpk2);
    bsel[3] = (int)(g2 ? fpk7 : fpk3);
    short8 bf3 = __builtin_bit_cast(short8, bsel);
    floatx16 s3 = __builtin_amdgcn_mfma_f32_32x32x16_bf16(ab3, bf3, z16, 0, 0, 0);
    floatx2 Sb[4];   // Sb[r] = {S[2r], S[2r+1]}, S-slot j in 0..7
#pragma unroll
    for (int r = 0; r < 4; ++r) { Sb[r][0] = s3[2 * r]; Sb[r][1] = s3[2 * r + 1]; }

    // ---- stage-B + f-contraction: 8 io-tiles x 2 chained MFMAs ----
#pragma unroll
    for (int t2 = 0; t2 < 8; ++t2) {
      short8 w0 = buP[(t2 * 2 + 0) * 64];
      short8 w1 = buP[(t2 * 2 + 1) * 64];
      floatx16 u0 = __builtin_amdgcn_mfma_f32_32x32x16_bf16(w0, bh2k0, z16, 0, 0, 0);
      floatx16 dd = __builtin_amdgcn_mfma_f32_32x32x16_bf16(w1, bh2k1, u0, 0, 0, 0);
      unsigned fw;
      switch (t2) {   // compile-time unrolled: static selection, no indexing
        case 0: fw = fpk0; break; case 1: fw = fpk1; break;
        case 2: fw = fpk2; break; case 3: fw = fpk3; break;
        case 4: fw = fpk4; break; case 5: fw = fpk5; break;
        case 6: fw = fpk6; break; default: fw = fpk7; break;
      }
      const float fe = __builtin_bit_cast(float, (int)(fw << 16));          // f[2t2]
      const float fo = __builtin_bit_cast(float, (int)(fw & 0xffff0000u));  // f[2t2+1]
      const floatx2 fe2 = {fe, fe}, fo2 = {fo, fo};
#pragma unroll
      for (int r = 0; r < 4; ++r) {
        floatx2 lo = {dd[2 * r],     dd[2 * r + 1]};       // rows i=2t2
        floatx2 hi = {dd[8 + 2 * r], dd[8 + 2 * r + 1]};   // rows i=2t2+1
        Sb[r] = __builtin_elementwise_fma(fe2, lo, Sb[r]);
        Sb[r] = __builtin_elementwise_fma(fo2, hi, Sb[r]);
      }
      if (t2 & 1) __builtin_amdgcn_sched_barrier(0);
    }

    float Sa[8];
#pragma unroll
    for (int r = 0; r < 4; ++r) { Sa[2 * r] = Sb[r][0]; Sa[2 * r + 1] = Sb[r][1]; }

    // ---- segment sum over each query's 16 cols: DPP butterfly ----
#pragma unroll
    for (int j = 0; j < 8; ++j) Sa[j] = dpp_add<0xB1>(Sa[j]);
#pragma unroll
    for (int j = 0; j < 8; ++j) Sa[j] = dpp_add<0x4E>(Sa[j]);
#pragma unroll
    for (int j = 0; j < 8; ++j) Sa[j] = dpp_add<0x124>(Sa[j]);
#pragma unroll
    for (int j = 0; j < 8; ++j) Sa[j] = dpp_add<0x128>(Sa[j]);

    if (c16 == 0) {
      const int qq = 2 * p + qh;
      if (qq < Nq) {
        float* op = out + (size_t)qq * 16 + 4 * g2;
        float4 lo = {Sa[0], Sa[1], Sa[2], Sa[3]};   // o = 4g2 .. 4g2+3
        float4 hi = {Sa[4], Sa[5], Sa[6], Sa[7]};   // o = 4g2+8 .. 4g2+11
        *reinterpret_cast<float4*>(op)     = lo;
        *reinterpret_cast<float4*>(op + 8) = hi;
      }
    }
  }
}

extern "C" void kernel_launch(void* const* d_in, const int* in_sizes, int n_in,
                              void* d_out, int out_size, void* d_ws, size_t ws_size,
                              hipStream_t stream) {
  const float* feats = (const float*)d_in[0];
  const float* xyz   = (const float*)d_in[1];
  const int*   nbr   = (const int*)d_in[2];
  // d_in[3] = neighbors_row_splits: uniform arange*16 for this problem
  const float* dist  = (const float*)d_in[4];
  const float* W1 = (const float*)d_in[5];
  const float* b1 = (const float*)d_in[6];
  const float* W2 = (const float*)d_in[7];
  const float* b2 = (const float*)d_in[8];
  const float* W3 = (const float*)d_in[9];
  const float* b3 = (const float*)d_in[10];
  float* out = (float*)d_out;

  const int Nq = in_sizes[3] - 1;

  polarconv_v14<<<NBLOCKS, THREADS, 0, stream>>>(
      feats, xyz, nbr, dist, W1, b1, W2, b2, W3, b3, out, Nq);
}